// Round 5
// baseline (470.354 us; speedup 1.0000x reference)
//
#include <hip/hip_runtime.h>
#include <hip/hip_bf16.h>

#define N_TOK  4096
#define HD     512   // H * 64
#define NH     8
#define NSPLIT 4

typedef short v8s __attribute__((ext_vector_type(8)));
typedef float v4f __attribute__((ext_vector_type(4)));
typedef unsigned short u16;

#define QSCALE   0.18033688011112042f   // log2(e)/8  (folded into q at projection)
#define ADJ2     0.14426950408889634f   // 0.1*log2(e) (folded into E=exp2(ADJ2*adj))
#define SIG2P    1.4426950408889634f    // log2(e)

__device__ __forceinline__ float bf2f(u16 x) {
  union { unsigned int u; float f; } c; c.u = ((unsigned int)x) << 16; return c.f;
}
__device__ __forceinline__ u16 f2bf(float f) {
  union { float f; unsigned int u; } c; c.f = f;
  return (u16)((c.u + 0x7fffu + ((c.u >> 16) & 1u)) >> 16);
}
__device__ __forceinline__ float fast_exp2(float x) {
#if __has_builtin(__builtin_amdgcn_exp2f)
  return __builtin_amdgcn_exp2f(x);
#else
  return exp2f(x);
#endif
}
__device__ __forceinline__ unsigned int pk_bf16(float a, float b) {
  union { __hip_bfloat162 h; unsigned int u; } c;
  c.h = __float22bfloat162_rn(make_float2(a, b));
  return c.u;
}

// ---------- inline dtype detect: true -> inputs are fp32 (read from Q's first 128 u16) ----------
// bf16 data: even u16s are genuine N(0,1) bf16 -> nearly all "plausible".
// fp32 data: even u16s are low mantissa bits -> ~42% plausible.
__device__ __forceinline__ bool detect_f32(const u16* __restrict__ q) {
  int l = threadIdx.x & 63;
  u16 e = q[2 * l];
  float x = bf2f(e);
  int ex = (e >> 7) & 0xFF;
  float ax = fabsf(x);
  bool ok = (ex != 0xFF) && (ax < 64.f) && (ax > 1e-30f);
  unsigned long long m = __ballot(ok);
  return __popcll(m) < 48;
}
__device__ __forceinline__ float bias_ld(const void* b, int i, bool f32) {
  return f32 ? ((const float*)b)[i] : bf2f(((const u16*)b)[i]);
}

// ---------- adjE = exp2(ADJ2*adj) in bf16 ----------
__global__ __launch_bounds__(256) void conv_adjE_k(const void* __restrict__ adj, u16* __restrict__ adjE,
                                                   const u16* __restrict__ Qdet) {
  bool f32 = detect_f32(Qdet);
  int i = blockIdx.x * 256 + threadIdx.x;   // 4 elems/thread, grid covers N*N/4 exactly
  float4 f;
  if (f32) {
    f = ((const float4*)adj)[i];
  } else {
    short4 v = ((const short4*)adj)[i];
    f.x = bf2f((u16)v.x); f.y = bf2f((u16)v.y); f.z = bf2f((u16)v.z); f.w = bf2f((u16)v.w);
  }
  unsigned int d0 = pk_bf16(fast_exp2(f.x * ADJ2), fast_exp2(f.y * ADJ2));
  unsigned int d1 = pk_bf16(fast_exp2(f.z * ADJ2), fast_exp2(f.w * ADJ2));
  ((uint2*)adjE)[i] = make_uint2(d0, d1);
}

// ---------- fused convert+transpose for all 4 weights: out[C][R] = bf16(in[R][C]) ----------
__global__ __launch_bounds__(256) void tr_w_k(const void* W0, const void* W1, const void* W2, const void* W3,
                                              u16* t0, u16* t1, u16* t2, u16* t3,
                                              const u16* __restrict__ Qdet) {
  bool f32 = detect_f32(Qdet);
  int z = blockIdx.z;
  const void* in; u16* out; int C;
  if (z == 0)      { in = W0; out = t0; C = 512; }
  else if (z == 1) { in = W1; out = t1; C = 512; }
  else if (z == 2) { in = W2; out = t2; C = 512; }
  else             { in = W3; out = t3; C = 64; if (blockIdx.y) return; }
  const int R = 512;
  __shared__ __align__(16) u16 tile[64][72];
  const int r0 = blockIdx.x * 64, c0 = blockIdx.y * 64;
  const int t = threadIdx.x;
#pragma unroll
  for (int rep = 0; rep < 2; ++rep) {
    int idx = (t + rep * 256) * 8;
    int r = idx >> 6, c = idx & 63;
    if (f32) {
      const float* sp = (const float*)in + (size_t)(r0 + r) * C + (c0 + c);
      float4 a = *(const float4*)sp, b = *(const float4*)(sp + 4);
      uint4 q = make_uint4(pk_bf16(a.x, a.y), pk_bf16(a.z, a.w),
                           pk_bf16(b.x, b.y), pk_bf16(b.z, b.w));
      *(uint4*)&tile[r][c] = q;
    } else {
      *(v8s*)&tile[r][c] = *(const v8s*)((const u16*)in + (size_t)(r0 + r) * C + (c0 + c));
    }
  }
  __syncthreads();
#pragma unroll
  for (int rep = 0; rep < 2; ++rep) {
    int idx = (t + rep * 256) * 8;
    int oc = idx >> 6, orr = idx & 63;
    u16 tmp[8];
#pragma unroll
    for (int j = 0; j < 8; ++j) tmp[j] = tile[orr + j][oc];
    *(v8s*)(out + (size_t)(c0 + oc) * R + (r0 + orr)) = *(v8s*)tmp;
  }
}

// ---------- batched Q/K/V projection GEMM; z==0 scales q; z==2 writes output TRANSPOSED ----------
__global__ __launch_bounds__(256) void gemm_qkv_k(const void* A0, const void* A1, const void* A2,
                                                  const u16* __restrict__ t0, const u16* __restrict__ t1,
                                                  const u16* __restrict__ t2,
                                                  const void* b0, const void* b1, const void* b2,
                                                  u16* __restrict__ qb, u16* __restrict__ kb,
                                                  u16* __restrict__ vtb) {
  __shared__ __align__(16) u16 As[64][72];
  __shared__ __align__(16) u16 Bs[64][72];
  bool f32 = detect_f32((const u16*)A0);
  int z = blockIdx.z;
  const void* Araw = (z == 0) ? A0 : (z == 1) ? A1 : A2;
  const u16* Bt    = (z == 0) ? t0 : (z == 1) ? t1 : t2;
  const void* bias = (z == 0) ? b0 : (z == 1) ? b1 : b2;
  const bool vt = (z == 2);
  const int i0 = blockIdx.x * 64, j0 = blockIdx.y * 64;
  const int t = threadIdx.x, w = t >> 6, l = t & 63, quad = l >> 4, l15 = l & 15;
  v4f acc[4] = {};
  for (int k0 = 0; k0 < 512; k0 += 64) {
#pragma unroll
    for (int rep = 0; rep < 2; ++rep) {
      int idx = (t + rep * 256) * 8;
      int r = idx >> 6, c = idx & 63;
      if (f32) {
        const float* sp = (const float*)Araw + (size_t)(i0 + r) * 512 + k0 + c;
        float4 fa = *(const float4*)sp, fb = *(const float4*)(sp + 4);
        uint4 q = make_uint4(pk_bf16(fa.x, fa.y), pk_bf16(fa.z, fa.w),
                             pk_bf16(fb.x, fb.y), pk_bf16(fb.z, fb.w));
        *(uint4*)&As[r][c] = q;
      } else {
        *(v8s*)&As[r][c] = *(const v8s*)((const u16*)Araw + (size_t)(i0 + r) * 512 + k0 + c);
      }
      *(v8s*)&Bs[r][c] = *(const v8s*)(Bt + (size_t)(j0 + r) * 512 + k0 + c);
    }
    __syncthreads();
    if (vt) {
#pragma unroll
      for (int h = 0; h < 2; ++h) {
        v8s a = *(const v8s*)&As[w * 16 + l15][h * 32 + quad * 8];
#pragma unroll
        for (int cb = 0; cb < 4; ++cb) {
          v8s b = *(const v8s*)&Bs[cb * 16 + l15][h * 32 + quad * 8];
          acc[cb] = __builtin_amdgcn_mfma_f32_16x16x32_bf16(b, a, acc[cb], 0, 0, 0);  // swapped -> C^T
        }
      }
    } else {
#pragma unroll
      for (int h = 0; h < 2; ++h) {
        v8s a = *(const v8s*)&As[w * 16 + l15][h * 32 + quad * 8];
#pragma unroll
        for (int cb = 0; cb < 4; ++cb) {
          v8s b = *(const v8s*)&Bs[cb * 16 + l15][h * 32 + quad * 8];
          acc[cb] = __builtin_amdgcn_mfma_f32_16x16x32_bf16(a, b, acc[cb], 0, 0, 0);
        }
      }
    }
    __syncthreads();
  }
  if (vt) {
    // D rows = weight-out dim j, cols = token dim i -> store v^T[j][i]
#pragma unroll
    for (int cb = 0; cb < 4; ++cb) {
#pragma unroll
      for (int r = 0; r < 4; ++r) {
        int jj = j0 + cb * 16 + quad * 4 + r;
        int ii = i0 + w * 16 + l15;
        vtb[(size_t)jj * N_TOK + ii] = f2bf(acc[cb][r] + bias_ld(bias, jj, f32));
      }
    }
  } else {
    const float oscale = (z == 0) ? QSCALE : 1.0f;
    u16* C = (z == 0) ? qb : kb;
#pragma unroll
    for (int cb = 0; cb < 4; ++cb) {
      int col = j0 + cb * 16 + l15;
      float bv = bias_ld(bias, col, f32);
#pragma unroll
      for (int r = 0; r < 4; ++r) {
        int row = i0 + w * 16 + quad * 4 + r;
        C[(size_t)row * HD + col] = f2bf((acc[cb][r] + bv) * oscale);
      }
    }
  }
}

// ---------- fused attention, barrier-free: direct-global K/V fragments, LDS only for P ----------
// qb pre-scaled by QSCALE; adjE = exp2(ADJ2*adj). Block = (64 q-rows, head, split).
__global__ __launch_bounds__(256, 4) void attn_kernel(const u16* __restrict__ qb, const u16* __restrict__ kb,
                                                      const u16* __restrict__ vtb, const u16* __restrict__ adjE,
                                                      u16* __restrict__ Opart, float* __restrict__ Lpart) {
  __shared__ __align__(16) u16 Ps[4][16][72];   // per-wave private P[i][m]
  const int i0 = blockIdx.x * 64, h64 = blockIdx.y * 64, z = blockIdx.z;
  const int t = threadIdx.x, w = t >> 6, l = t & 63, quad = l >> 4, l15 = l & 15;
  const int iRow = i0 + w * 16 + l15;          // this lane's q-row

  v8s qf[2];
#pragma unroll
  for (int h = 0; h < 2; ++h)
    qf[h] = *(const v8s*)(qb + (size_t)iRow * HD + h64 + h * 32 + quad * 8);

  const u16* adjRow = adjE + (size_t)iRow * N_TOK;
  v4f oacc[4] = {};
  float lsum = 0.f;

  const int m_begin = z * (N_TOK / NSPLIT);
  for (int m0 = m_begin; m0 < m_begin + N_TOK / NSPLIT; m0 += 64) {
    uint2 av[4];
#pragma unroll
    for (int cb = 0; cb < 4; ++cb)
      av[cb] = *(const uint2*)(adjRow + m0 + cb * 16 + quad * 4);

    // S^T = K @ q^T : K fragments straight from global (identical across waves -> L1 reuse)
    v4f s[4] = {};
#pragma unroll
    for (int h = 0; h < 2; ++h) {
#pragma unroll
      for (int cb = 0; cb < 4; ++cb) {
        v8s kf = *(const v8s*)(kb + (size_t)(m0 + cb * 16 + l15) * HD + h64 + h * 32 + quad * 8);
        s[cb] = __builtin_amdgcn_mfma_f32_16x16x32_bf16(kf, qf[h], s[cb], 0, 0, 0);
      }
    }

    // p = exp2(sig*log2e) * E  (constants cancel in normalization)
#pragma unroll
    for (int cb = 0; cb < 4; ++cb) {
      union { unsigned int u; float f; } e0, e1, e2, e3;
      e0.u = av[cb].x << 16; e1.u = av[cb].x & 0xFFFF0000u;
      e2.u = av[cb].y << 16; e3.u = av[cb].y & 0xFFFF0000u;
      float u0 = fast_exp2(-s[cb][0]); float p0 = fast_exp2(__builtin_amdgcn_rcpf(1.f + u0) * SIG2P) * e0.f;
      float u1 = fast_exp2(-s[cb][1]); float p1 = fast_exp2(__builtin_amdgcn_rcpf(1.f + u1) * SIG2P) * e1.f;
      float u2 = fast_exp2(-s[cb][2]); float p2 = fast_exp2(__builtin_amdgcn_rcpf(1.f + u2) * SIG2P) * e2.f;
      float u3 = fast_exp2(-s[cb][3]); float p3 = fast_exp2(__builtin_amdgcn_rcpf(1.f + u3) * SIG2P) * e3.f;
      lsum += (p0 + p1) + (p2 + p3);
      *(uint2*)&Ps[w][l15][cb * 16 + quad * 4] = make_uint2(pk_bf16(p0, p1), pk_bf16(p2, p3));
    }
    asm volatile("s_waitcnt lgkmcnt(0)" ::: "memory");  // Ps is wave-private: order write->read

    // O += P @ v : V fragments straight from global
#pragma unroll
    for (int h = 0; h < 2; ++h) {
      v8s pa = *(const v8s*)&Ps[w][l15][h * 32 + quad * 8];
#pragma unroll
      for (int eb = 0; eb < 4; ++eb) {
        v8s vf = *(const v8s*)(vtb + (size_t)(h64 + eb * 16 + l15) * N_TOK + m0 + h * 32 + quad * 8);
        oacc[eb] = __builtin_amdgcn_mfma_f32_16x16x32_bf16(pa, vf, oacc[eb], 0, 0, 0);
      }
    }
  }

  lsum += __shfl_xor(lsum, 16);
  lsum += __shfl_xor(lsum, 32);
  if (l < 16)
    Lpart[((size_t)z * N_TOK + i0 + w * 16 + l) * NH + blockIdx.y] = lsum;
#pragma unroll
  for (int eb = 0; eb < 4; ++eb) {
#pragma unroll
    for (int r = 0; r < 4; ++r) {
      size_t row = (size_t)z * N_TOK + i0 + w * 16 + quad * 4 + r;
      Opart[row * HD + h64 + eb * 16 + l15] = f2bf(oacc[eb][r]);
    }
  }
}

// ---------- final projection with fused split-combine:
// A-tile = (sum_s Opart)/(sum_s Lpart), then C = A @ tO^T + bO (fp32/bf16 out by flag) ----------
__global__ __launch_bounds__(256) void gemm_bt(const u16* __restrict__ Opart, const float* __restrict__ Lpart,
                                               const u16* __restrict__ Bt, const void* bias,
                                               void* __restrict__ C, const u16* __restrict__ Qdet) {
  __shared__ __align__(16) u16 As[64][72];
  __shared__ __align__(16) u16 Bs[64][72];
  bool f32 = detect_f32(Qdet);
  const int i0 = blockIdx.x * 64;
  const int t = threadIdx.x, w = t >> 6, l = t & 63, quad = l >> 4, l15 = l & 15;
  v4f acc[4] = {};
  for (int k0 = 0; k0 < 512; k0 += 64) {
    const int h = k0 >> 6;
#pragma unroll
    for (int rep = 0; rep < 2; ++rep) {
      int idx = (t + rep * 256) * 8;
      int r = idx >> 6, c = idx & 63;
      // normalizer for (row i0+r, head h)
      float lv = 0.f;
#pragma unroll
      for (int s = 0; s < NSPLIT; ++s) lv += Lpart[((size_t)s * N_TOK + i0 + r) * NH + h];
      float rl = __builtin_amdgcn_rcpf(lv);
      float vals[8] = {};
#pragma unroll
      for (int s = 0; s < NSPLIT; ++s) {
        v8s ov = *(const v8s*)(Opart + ((size_t)s * N_TOK + i0 + r) * HD + k0 + c);
#pragma unroll
        for (int j = 0; j < 8; ++j) vals[j] += bf2f((u16)ov[j]);
      }
      uint4 q = make_uint4(pk_bf16(vals[0] * rl, vals[1] * rl), pk_bf16(vals[2] * rl, vals[3] * rl),
                           pk_bf16(vals[4] * rl, vals[5] * rl), pk_bf16(vals[6] * rl, vals[7] * rl));
      *(uint4*)&As[r][c] = q;
      *(v8s*)&Bs[r][c] = *(const v8s*)(Bt + (size_t)r * 512 + k0 + c);   // NB=64 -> j0=0
    }
    __syncthreads();
#pragma unroll
    for (int h2 = 0; h2 < 2; ++h2) {
      v8s a = *(const v8s*)&As[w * 16 + l15][h2 * 32 + quad * 8];
#pragma unroll
      for (int cb = 0; cb < 4; ++cb) {
        v8s b = *(const v8s*)&Bs[cb * 16 + l15][h2 * 32 + quad * 8];
        acc[cb] = __builtin_amdgcn_mfma_f32_16x16x32_bf16(a, b, acc[cb], 0, 0, 0);
      }
    }
    __syncthreads();
  }
#pragma unroll
  for (int cb = 0; cb < 4; ++cb) {
    int col = cb * 16 + l15;
    float bv = bias_ld(bias, col, f32);
#pragma unroll
    for (int r = 0; r < 4; ++r) {
      int row = i0 + w * 16 + quad * 4 + r;
      float v = acc[cb][r] + bv;
      size_t idx = (size_t)row * 64 + col;
      if (f32) ((float*)C)[idx] = v;
      else     ((u16*)C)[idx] = f2bf(v);
    }
  }
}

extern "C" void kernel_launch(void* const* d_in, const int* in_sizes, int n_in,
                              void* d_out, int out_size, void* d_ws, size_t ws_size,
                              hipStream_t stream) {
  (void)in_sizes; (void)n_in; (void)out_size; (void)ws_size;
  const void* Q   = d_in[0];
  const void* K   = d_in[1];
  const void* V   = d_in[2];
  const void* adj = d_in[3];
  const void* WQ  = d_in[4];
  const void* bQ  = d_in[5];
  const void* WK  = d_in[6];
  const void* bK  = d_in[7];
  const void* WV  = d_in[8];
  const void* bV  = d_in[9];
  const void* WO  = d_in[10];
  const void* bO  = d_in[11];
  const u16* Qdet = (const u16*)Q;

  char* p = (char*)d_ws;
  auto alloc = [&](size_t bytes) { char* r = p; p += (bytes + 255) & ~(size_t)255; return r; };
  const size_t SZ = (size_t)N_TOK * HD * 2;

  u16* adjE    = (u16*)alloc((size_t)N_TOK * N_TOK * 2);
  u16* qb      = (u16*)alloc(SZ);
  u16* kb      = (u16*)alloc(SZ);
  u16* vtb     = (u16*)alloc(SZ);
  u16* Opart   = (u16*)alloc((size_t)NSPLIT * SZ);
  float* Lpart = (float*)alloc((size_t)NSPLIT * N_TOK * NH * 4);
  u16* tQ      = (u16*)alloc((size_t)512 * 512 * 2);
  u16* tK      = (u16*)alloc((size_t)512 * 512 * 2);
  u16* tV      = (u16*)alloc((size_t)512 * 512 * 2);
  u16* tO      = (u16*)alloc((size_t)64 * 512 * 2);

  dim3 b256(256);
  conv_adjE_k<<<dim3(16384), b256, 0, stream>>>(adj, adjE, Qdet);
  tr_w_k<<<dim3(8, 8, 4), b256, 0, stream>>>(WQ, WK, WV, WO, tQ, tK, tV, tO, Qdet);
  gemm_qkv_k<<<dim3(64, 8, 3), b256, 0, stream>>>(Q, K, V, tQ, tK, tV,
                                                  bQ, bK, bV, qb, kb, vtb);
  attn_kernel<<<dim3(N_TOK / 64, NH, NSPLIT), b256, 0, stream>>>(qb, kb, vtb, adjE, Opart, Lpart);
  gemm_bt<<<dim3(64, 1), b256, 0, stream>>>(Opart, Lpart, tO, bO, d_out, Qdet);
}

// Round 6
// 270.655 us; speedup vs baseline: 1.7378x; 1.7378x over previous
//
#include <hip/hip_runtime.h>
#include <hip/hip_bf16.h>

#define N_TOK  4096
#define HD     512   // H * 64
#define NH     8
#define NSPLIT 2

typedef short v8s __attribute__((ext_vector_type(8)));
typedef float v4f __attribute__((ext_vector_type(4)));
typedef unsigned short u16;

#define QSCALE   0.18033688011112042f   // log2(e)/8  (folded into q at projection)
#define ADJ2     0.14426950408889634f   // 0.1*log2(e) (folded into E=exp2(ADJ2*adj))
// minimax cubic for e^x on [0,1]: max abs err ~5.5e-4 (<< bf16 P quantization 4e-3)
#define EA0 0.999410f
#define EA1 1.016220f
#define EA2 0.423120f
#define EA3 0.279120f

__device__ __forceinline__ float bf2f(u16 x) {
  union { unsigned int u; float f; } c; c.u = ((unsigned int)x) << 16; return c.f;
}
__device__ __forceinline__ u16 f2bf(float f) {
  union { float f; unsigned int u; } c; c.f = f;
  return (u16)((c.u + 0x7fffu + ((c.u >> 16) & 1u)) >> 16);
}
__device__ __forceinline__ float fast_exp2(float x) {
#if __has_builtin(__builtin_amdgcn_exp2f)
  return __builtin_amdgcn_exp2f(x);
#else
  return exp2f(x);
#endif
}
__device__ __forceinline__ unsigned int pk_bf16(float a, float b) {
  union { __hip_bfloat162 h; unsigned int u; } c;
  c.h = __float22bfloat162_rn(make_float2(a, b));
  return c.u;
}

// ---------- inline dtype detect: true -> inputs are fp32 (read from Q's first 128 u16) ----------
__device__ __forceinline__ bool detect_f32(const u16* __restrict__ q) {
  int l = threadIdx.x & 63;
  u16 e = q[2 * l];
  float x = bf2f(e);
  int ex = (e >> 7) & 0xFF;
  float ax = fabsf(x);
  bool ok = (ex != 0xFF) && (ax < 64.f) && (ax > 1e-30f);
  unsigned long long m = __ballot(ok);
  return __popcll(m) < 48;
}
__device__ __forceinline__ float bias_ld(const void* b, int i, bool f32) {
  return f32 ? ((const float*)b)[i] : bf2f(((const u16*)b)[i]);
}

// ---------- adjE = exp2(ADJ2*adj) in bf16 ----------
__global__ __launch_bounds__(256) void conv_adjE_k(const void* __restrict__ adj, u16* __restrict__ adjE,
                                                   const u16* __restrict__ Qdet) {
  bool f32 = detect_f32(Qdet);
  int i = blockIdx.x * 256 + threadIdx.x;   // 4 elems/thread, grid covers N*N/4 exactly
  float4 f;
  if (f32) {
    f = ((const float4*)adj)[i];
  } else {
    short4 v = ((const short4*)adj)[i];
    f.x = bf2f((u16)v.x); f.y = bf2f((u16)v.y); f.z = bf2f((u16)v.z); f.w = bf2f((u16)v.w);
  }
  unsigned int d0 = pk_bf16(fast_exp2(f.x * ADJ2), fast_exp2(f.y * ADJ2));
  unsigned int d1 = pk_bf16(fast_exp2(f.z * ADJ2), fast_exp2(f.w * ADJ2));
  ((uint2*)adjE)[i] = make_uint2(d0, d1);
}

// ---------- fused convert+transpose for all 4 weights: out[C][R] = bf16(in[R][C]) ----------
__global__ __launch_bounds__(256) void tr_w_k(const void* W0, const void* W1, const void* W2, const void* W3,
                                              u16* t0, u16* t1, u16* t2, u16* t3,
                                              const u16* __restrict__ Qdet) {
  bool f32 = detect_f32(Qdet);
  int z = blockIdx.z;
  const void* in; u16* out; int C;
  if (z == 0)      { in = W0; out = t0; C = 512; }
  else if (z == 1) { in = W1; out = t1; C = 512; }
  else if (z == 2) { in = W2; out = t2; C = 512; }
  else             { in = W3; out = t3; C = 64; if (blockIdx.y) return; }
  const int R = 512;
  __shared__ __align__(16) u16 tile[64][72];
  const int r0 = blockIdx.x * 64, c0 = blockIdx.y * 64;
  const int t = threadIdx.x;
#pragma unroll
  for (int rep = 0; rep < 2; ++rep) {
    int idx = (t + rep * 256) * 8;
    int r = idx >> 6, c = idx & 63;
    if (f32) {
      const float* sp = (const float*)in + (size_t)(r0 + r) * C + (c0 + c);
      float4 a = *(const float4*)sp, b = *(const float4*)(sp + 4);
      uint4 q = make_uint4(pk_bf16(a.x, a.y), pk_bf16(a.z, a.w),
                           pk_bf16(b.x, b.y), pk_bf16(b.z, b.w));
      *(uint4*)&tile[r][c] = q;
    } else {
      *(v8s*)&tile[r][c] = *(const v8s*)((const u16*)in + (size_t)(r0 + r) * C + (c0 + c));
    }
  }
  __syncthreads();
#pragma unroll
  for (int rep = 0; rep < 2; ++rep) {
    int idx = (t + rep * 256) * 8;
    int oc = idx >> 6, orr = idx & 63;
    u16 tmp[8];
#pragma unroll
    for (int j = 0; j < 8; ++j) tmp[j] = tile[orr + j][oc];
    *(v8s*)(out + (size_t)(c0 + oc) * R + (r0 + orr)) = *(v8s*)tmp;
  }
}

// ---------- batched Q/K/V projection GEMM; z==0 scales q; z==2 writes output TRANSPOSED ----------
__global__ __launch_bounds__(256) void gemm_qkv_k(const void* A0, const void* A1, const void* A2,
                                                  const u16* __restrict__ t0, const u16* __restrict__ t1,
                                                  const u16* __restrict__ t2,
                                                  const void* b0, const void* b1, const void* b2,
                                                  u16* __restrict__ qb, u16* __restrict__ kb,
                                                  u16* __restrict__ vtb) {
  __shared__ __align__(16) u16 As[64][72];
  __shared__ __align__(16) u16 Bs[64][72];
  bool f32 = detect_f32((const u16*)A0);
  int z = blockIdx.z;
  const void* Araw = (z == 0) ? A0 : (z == 1) ? A1 : A2;
  const u16* Bt    = (z == 0) ? t0 : (z == 1) ? t1 : t2;
  const void* bias = (z == 0) ? b0 : (z == 1) ? b1 : b2;
  const bool vt = (z == 2);
  const int i0 = blockIdx.x * 64, j0 = blockIdx.y * 64;
  const int t = threadIdx.x, w = t >> 6, l = t & 63, quad = l >> 4, l15 = l & 15;
  v4f acc[4] = {};
  for (int k0 = 0; k0 < 512; k0 += 64) {
#pragma unroll
    for (int rep = 0; rep < 2; ++rep) {
      int idx = (t + rep * 256) * 8;
      int r = idx >> 6, c = idx & 63;
      if (f32) {
        const float* sp = (const float*)Araw + (size_t)(i0 + r) * 512 + k0 + c;
        float4 fa = *(const float4*)sp, fb = *(const float4*)(sp + 4);
        uint4 q = make_uint4(pk_bf16(fa.x, fa.y), pk_bf16(fa.z, fa.w),
                             pk_bf16(fb.x, fb.y), pk_bf16(fb.z, fb.w));
        *(uint4*)&As[r][c] = q;
      } else {
        *(v8s*)&As[r][c] = *(const v8s*)((const u16*)Araw + (size_t)(i0 + r) * 512 + k0 + c);
      }
      *(v8s*)&Bs[r][c] = *(const v8s*)(Bt + (size_t)(j0 + r) * 512 + k0 + c);
    }
    __syncthreads();
    if (vt) {
#pragma unroll
      for (int h = 0; h < 2; ++h) {
        v8s a = *(const v8s*)&As[w * 16 + l15][h * 32 + quad * 8];
#pragma unroll
        for (int cb = 0; cb < 4; ++cb) {
          v8s b = *(const v8s*)&Bs[cb * 16 + l15][h * 32 + quad * 8];
          acc[cb] = __builtin_amdgcn_mfma_f32_16x16x32_bf16(b, a, acc[cb], 0, 0, 0);  // swapped -> C^T
        }
      }
    } else {
#pragma unroll
      for (int h = 0; h < 2; ++h) {
        v8s a = *(const v8s*)&As[w * 16 + l15][h * 32 + quad * 8];
#pragma unroll
        for (int cb = 0; cb < 4; ++cb) {
          v8s b = *(const v8s*)&Bs[cb * 16 + l15][h * 32 + quad * 8];
          acc[cb] = __builtin_amdgcn_mfma_f32_16x16x32_bf16(a, b, acc[cb], 0, 0, 0);
        }
      }
    }
    __syncthreads();
  }
  if (vt) {
#pragma unroll
    for (int cb = 0; cb < 4; ++cb) {
#pragma unroll
      for (int r = 0; r < 4; ++r) {
        int jj = j0 + cb * 16 + quad * 4 + r;
        int ii = i0 + w * 16 + l15;
        vtb[(size_t)jj * N_TOK + ii] = f2bf(acc[cb][r] + bias_ld(bias, jj, f32));
      }
    }
  } else {
    const float oscale = (z == 0) ? QSCALE : 1.0f;
    u16* C = (z == 0) ? qb : kb;
#pragma unroll
    for (int cb = 0; cb < 4; ++cb) {
      int col = j0 + cb * 16 + l15;
      float bv = bias_ld(bias, col, f32);
#pragma unroll
      for (int r = 0; r < 4; ++r) {
        int row = i0 + w * 16 + quad * 4 + r;
        C[(size_t)row * HD + col] = f2bf((acc[cb][r] + bv) * oscale);
      }
    }
  }
}

// ---------- fused attention (S^T scheme, LDS-staged K/V — the R4 known-good structure) ----------
// qb pre-scaled by QSCALE; adjE = exp2(ADJ2*adj). Block = (64 q-rows, head, split).
__global__ __launch_bounds__(256, 4) void attn_kernel(const u16* __restrict__ qb, const u16* __restrict__ kb,
                                                      const u16* __restrict__ vtb, const u16* __restrict__ adjE,
                                                      u16* __restrict__ Opart, float* __restrict__ Lpart) {
  __shared__ __align__(16) u16 Ks[64][72];
  __shared__ __align__(16) u16 Vs[64][72];      // Vs[e][m]
  __shared__ __align__(16) u16 Ps[4][16][72];   // per-wave private P[i][m]
  const int i0 = blockIdx.x * 64, h64 = blockIdx.y * 64, z = blockIdx.z;
  const int t = threadIdx.x, w = t >> 6, l = t & 63, quad = l >> 4, l15 = l & 15;
  const int iRow = i0 + w * 16 + l15;          // this lane's q-row

  v8s qf[2];
#pragma unroll
  for (int h = 0; h < 2; ++h)
    qf[h] = *(const v8s*)(qb + (size_t)iRow * HD + h64 + h * 32 + quad * 8);

  const u16* adjRow = adjE + (size_t)iRow * N_TOK;
  v4f oacc[4] = {};
  float lsum = 0.f;

  const int m_begin = z * (N_TOK / NSPLIT);
  for (int m0 = m_begin; m0 < m_begin + N_TOK / NSPLIT; m0 += 64) {
    // per-lane adjE strip prefetch (row iRow, 4 chunks of 4) — overlaps staging
    uint2 av[4];
#pragma unroll
    for (int cb = 0; cb < 4; ++cb)
      av[cb] = *(const uint2*)(adjRow + m0 + cb * 16 + quad * 4);

#pragma unroll
    for (int rep = 0; rep < 2; ++rep) {
      int idx = (t + rep * 256) * 8;
      int r = idx >> 6, c = idx & 63;
      *(v8s*)&Ks[r][c] = *(const v8s*)(kb  + (size_t)(m0 + r) * HD + h64 + c);
      *(v8s*)&Vs[r][c] = *(const v8s*)(vtb + (size_t)(h64 + r) * N_TOK + m0 + c);
    }
    __syncthreads();

    // S^T = K @ q^T : lane owns q-row i=l15, keys m = m0+cb*16+quad*4+r
    v4f s[4] = {};
#pragma unroll
    for (int h = 0; h < 2; ++h) {
#pragma unroll
      for (int cb = 0; cb < 4; ++cb) {
        v8s kf = *(const v8s*)&Ks[cb * 16 + l15][h * 32 + quad * 8];
        s[cb] = __builtin_amdgcn_mfma_f32_16x16x32_bf16(kf, qf[h], s[cb], 0, 0, 0);
      }
    }

    // p = E * cubic(sigmoid)  — 2 trans (exp2, rcp) + 3 FMA per element
#pragma unroll
    for (int cb = 0; cb < 4; ++cb) {
      union { unsigned int u; float f; } e0, e1, e2, e3;
      e0.u = av[cb].x << 16; e1.u = av[cb].x & 0xFFFF0000u;
      e2.u = av[cb].y << 16; e3.u = av[cb].y & 0xFFFF0000u;
      float r0 = __builtin_amdgcn_rcpf(1.f + fast_exp2(-s[cb][0]));
      float r1 = __builtin_amdgcn_rcpf(1.f + fast_exp2(-s[cb][1]));
      float r2 = __builtin_amdgcn_rcpf(1.f + fast_exp2(-s[cb][2]));
      float r3 = __builtin_amdgcn_rcpf(1.f + fast_exp2(-s[cb][3]));
      float p0 = e0.f * fmaf(fmaf(fmaf(EA3, r0, EA2), r0, EA1), r0, EA0);
      float p1 = e1.f * fmaf(fmaf(fmaf(EA3, r1, EA2), r1, EA1), r1, EA0);
      float p2 = e2.f * fmaf(fmaf(fmaf(EA3, r2, EA2), r2, EA1), r2, EA0);
      float p3 = e3.f * fmaf(fmaf(fmaf(EA3, r3, EA2), r3, EA1), r3, EA0);
      lsum += (p0 + p1) + (p2 + p3);
      *(uint2*)&Ps[w][l15][cb * 16 + quad * 4] = make_uint2(pk_bf16(p0, p1), pk_bf16(p2, p3));
    }
    asm volatile("s_waitcnt lgkmcnt(0)" ::: "memory");  // Ps is wave-private: order write->read

    // O += P @ v
#pragma unroll
    for (int h = 0; h < 2; ++h) {
      v8s pa = *(const v8s*)&Ps[w][l15][h * 32 + quad * 8];
#pragma unroll
      for (int eb = 0; eb < 4; ++eb) {
        v8s vf = *(const v8s*)&Vs[eb * 16 + l15][h * 32 + quad * 8];
        oacc[eb] = __builtin_amdgcn_mfma_f32_16x16x32_bf16(pa, vf, oacc[eb], 0, 0, 0);
      }
    }
    __syncthreads();
  }

  lsum += __shfl_xor(lsum, 16);
  lsum += __shfl_xor(lsum, 32);
  if (l < 16)
    Lpart[((size_t)z * N_TOK + i0 + w * 16 + l) * NH + blockIdx.y] = lsum;
#pragma unroll
  for (int eb = 0; eb < 4; ++eb) {
#pragma unroll
    for (int r = 0; r < 4; ++r) {
      size_t row = (size_t)z * N_TOK + i0 + w * 16 + quad * 4 + r;
      Opart[row * HD + h64 + eb * 16 + l15] = f2bf(oacc[eb][r]);
    }
  }
}

// ---------- final projection with fused split-combine ----------
__global__ __launch_bounds__(256) void gemm_bt(const u16* __restrict__ Opart, const float* __restrict__ Lpart,
                                               const u16* __restrict__ Bt, const void* bias,
                                               void* __restrict__ C, const u16* __restrict__ Qdet) {
  __shared__ __align__(16) u16 As[64][72];
  __shared__ __align__(16) u16 Bs[64][72];
  bool f32 = detect_f32(Qdet);
  const int i0 = blockIdx.x * 64;
  const int t = threadIdx.x, w = t >> 6, l = t & 63, quad = l >> 4, l15 = l & 15;
  v4f acc[4] = {};
  for (int k0 = 0; k0 < 512; k0 += 64) {
    const int h = k0 >> 6;
#pragma unroll
    for (int rep = 0; rep < 2; ++rep) {
      int idx = (t + rep * 256) * 8;
      int r = idx >> 6, c = idx & 63;
      float lv = 0.f;
#pragma unroll
      for (int s = 0; s < NSPLIT; ++s) lv += Lpart[((size_t)s * N_TOK + i0 + r) * NH + h];
      float rl = __builtin_amdgcn_rcpf(lv);
      float vals[8] = {};
#pragma unroll
      for (int s = 0; s < NSPLIT; ++s) {
        v8s ov = *(const v8s*)(Opart + ((size_t)s * N_TOK + i0 + r) * HD + k0 + c);
#pragma unroll
        for (int j = 0; j < 8; ++j) vals[j] += bf2f((u16)ov[j]);
      }
      uint4 q = make_uint4(pk_bf16(vals[0] * rl, vals[1] * rl), pk_bf16(vals[2] * rl, vals[3] * rl),
                           pk_bf16(vals[4] * rl, vals[5] * rl), pk_bf16(vals[6] * rl, vals[7] * rl));
      *(uint4*)&As[r][c] = q;
      *(v8s*)&Bs[r][c] = *(const v8s*)(Bt + (size_t)r * 512 + k0 + c);   // NB=64 -> j0=0
    }
    __syncthreads();
#pragma unroll
    for (int h2 = 0; h2 < 2; ++h2) {
      v8s a = *(const v8s*)&As[w * 16 + l15][h2 * 32 + quad * 8];
#pragma unroll
      for (int cb = 0; cb < 4; ++cb) {
        v8s b = *(const v8s*)&Bs[cb * 16 + l15][h2 * 32 + quad * 8];
        acc[cb] = __builtin_amdgcn_mfma_f32_16x16x32_bf16(a, b, acc[cb], 0, 0, 0);
      }
    }
    __syncthreads();
  }
#pragma unroll
  for (int cb = 0; cb < 4; ++cb) {
    int col = cb * 16 + l15;
    float bv = bias_ld(bias, col, f32);
#pragma unroll
    for (int r = 0; r < 4; ++r) {
      int row = i0 + w * 16 + quad * 4 + r;
      float v = acc[cb][r] + bv;
      size_t idx = (size_t)row * 64 + col;
      if (f32) ((float*)C)[idx] = v;
      else     ((u16*)C)[idx] = f2bf(v);
    }
  }
}

extern "C" void kernel_launch(void* const* d_in, const int* in_sizes, int n_in,
                              void* d_out, int out_size, void* d_ws, size_t ws_size,
                              hipStream_t stream) {
  (void)in_sizes; (void)n_in; (void)out_size; (void)ws_size;
  const void* Q   = d_in[0];
  const void* K   = d_in[1];
  const void* V   = d_in[2];
  const void* adj = d_in[3];
  const void* WQ  = d_in[4];
  const void* bQ  = d_in[5];
  const void* WK  = d_in[6];
  const void* bK  = d_in[7];
  const void* WV  = d_in[8];
  const void* bV  = d_in[9];
  const void* WO  = d_in[10];
  const void* bO  = d_in[11];
  const u16* Qdet = (const u16*)Q;

  char* p = (char*)d_ws;
  auto alloc = [&](size_t bytes) { char* r = p; p += (bytes + 255) & ~(size_t)255; return r; };
  const size_t SZ = (size_t)N_TOK * HD * 2;

  u16* adjE    = (u16*)alloc((size_t)N_TOK * N_TOK * 2);
  u16* qb      = (u16*)alloc(SZ);
  u16* kb      = (u16*)alloc(SZ);
  u16* vtb     = (u16*)alloc(SZ);
  u16* Opart   = (u16*)alloc((size_t)NSPLIT * SZ);
  float* Lpart = (float*)alloc((size_t)NSPLIT * N_TOK * NH * 4);
  u16* tQ      = (u16*)alloc((size_t)512 * 512 * 2);
  u16* tK      = (u16*)alloc((size_t)512 * 512 * 2);
  u16* tV      = (u16*)alloc((size_t)512 * 512 * 2);
  u16* tO      = (u16*)alloc((size_t)64 * 512 * 2);

  dim3 b256(256);
  conv_adjE_k<<<dim3(16384), b256, 0, stream>>>(adj, adjE, Qdet);
  tr_w_k<<<dim3(8, 8, 4), b256, 0, stream>>>(WQ, WK, WV, WO, tQ, tK, tV, tO, Qdet);
  gemm_qkv_k<<<dim3(64, 8, 3), b256, 0, stream>>>(Q, K, V, tQ, tK, tV,
                                                  bQ, bK, bV, qb, kb, vtb);
  attn_kernel<<<dim3(N_TOK / 64, NH, NSPLIT), b256, 0, stream>>>(qb, kb, vtb, adjE, Opart, Lpart);
  gemm_bt<<<dim3(64, 1), b256, 0, stream>>>(Opart, Lpart, tO, bO, d_out, Qdet);
}